// Round 9
// baseline (138.090 us; speedup 1.0000x reference)
//
#include <hip/hip_runtime.h>

typedef __attribute__((ext_vector_type(8))) __bf16 bf16x8;
typedef __attribute__((ext_vector_type(4))) __bf16 bf16x4;
typedef __attribute__((ext_vector_type(4))) float f32x4;
typedef __attribute__((ext_vector_type(8))) _Float16 f16x8;

#define LOG2E 1.44269504088896340736f

__device__ __forceinline__ void async_load16(const void* g, void* l) {
  __builtin_amdgcn_global_load_lds(
      (const __attribute__((address_space(1))) void*)g,
      (__attribute__((address_space(3))) void*)l, 16, 0, 0);
}

__device__ __forceinline__ float fast_exp2(float x) {
#if __has_builtin(__builtin_amdgcn_exp2f)
  return __builtin_amdgcn_exp2f(x);
#else
  return __expf(x * 0.6931471805599453f);
#endif
}

// ---------------- fp32 -> bf16 convert (vectorized) ----------------
__global__ void cvt_f32_bf16(const float* __restrict__ in,
                             __bf16* __restrict__ out, int n4) {
  int i = blockIdx.x * blockDim.x + threadIdx.x;
  int stride = gridDim.x * blockDim.x;
  for (; i < n4; i += stride) {
    float4 v = ((const float4*)in)[i];
    bf16x4 o;
    o[0] = (__bf16)v.x; o[1] = (__bf16)v.y; o[2] = (__bf16)v.z; o[3] = (__bf16)v.w;
    ((bf16x4*)out)[i] = o;
  }
}

// ---------------- log2-domain bias table, per-lane fragment layout ----------
// ebT f16x8 index (((b*64+qt)*32+kt)*64 + lane); element [ni*4+r] =
//   (sigmoid(gbias[b][kt*32+16ni+ln][qt*16+4g+r]) - 0.5) * 10*alpha*log2e
__global__ __launch_bounds__(256) void build_ebias(
    const float* __restrict__ gbias, const float* __restrict__ bstr,
    _Float16* __restrict__ ebT) {
  const int gid = blockIdx.x * 256 + threadIdx.x;  // 4096 blocks
  const int lane = gid & 63;
  const int kt = (gid >> 6) & 31;
  const int qt = (gid >> 11) & 63;
  const int b = gid >> 17;
  const int g = lane >> 4, ln = lane & 15;
  const float alpha = 1.f / (1.f + __expf(-bstr[0]));
  const float bsc = 10.f * alpha * LOG2E;
  f16x8 o;
#pragma unroll
  for (int ni = 0; ni < 2; ++ni)
#pragma unroll
    for (int r = 0; r < 4; ++r) {
      float gv = gbias[(size_t)(b * 1024 + kt * 32 + ni * 16 + ln) * 1024 +
                       qt * 16 + g * 4 + r];
      float sg = 1.f / (1.f + __expf(-gv));
      o[ni * 4 + r] = (_Float16)((sg - 0.5f) * bsc);
    }
  *(f16x8*)(ebT + (size_t)gid * 8) = o;
}

// ---------------- C = (A @ Bm^T + bias) [*scale] ----------------
template <int MODE>
__global__ __launch_bounds__(256) void gemm_bt(
    const __bf16* __restrict__ A, const __bf16* __restrict__ Bm,
    const float* __restrict__ bias, void* __restrict__ C0,
    __bf16* __restrict__ vT, int M, int N, int K) {
  __shared__ __align__(16) char smem[32768];
  char* lA = smem;
  char* lB = smem + 16384;
  const int t = threadIdx.x;
  const int lane = t & 63;
  const int wid = t >> 6;
  const int wm = wid >> 1, wn = wid & 1;
  const int g = lane >> 4, ln = lane & 15;
  const int m0 = blockIdx.y * 128;
  const int n0 = blockIdx.x * 128;

  const int srow = t >> 3;
  const int sswz = ((t & 7) * 16) ^ ((srow & 7) << 4);
  const size_t KB = (size_t)K * 2;
  const char* gA = (const char*)A + (size_t)m0 * KB;
  const char* gB = (const char*)Bm + (size_t)n0 * KB;

  f32x4 acc[4][4] = {};

  for (int k0 = 0; k0 < K; k0 += 64) {
    __syncthreads();
#pragma unroll
    for (int c = 0; c < 4; ++c) {
      int row = srow + 32 * c;
      async_load16(gA + (size_t)row * KB + k0 * 2 + sswz, lA + c * 4096 + t * 16);
      async_load16(gB + (size_t)row * KB + k0 * 2 + sswz, lB + c * 4096 + t * 16);
    }
    __syncthreads();
#pragma unroll
    for (int ks = 0; ks < 2; ++ks) {
      bf16x8 af[4], bf[4];
#pragma unroll
      for (int i = 0; i < 4; ++i) {
        int ar = wm * 64 + i * 16 + ln;
        int byo = (ks * 64 + g * 16) ^ ((ar & 7) << 4);
        af[i] = *(const bf16x8*)(lA + ar * 128 + byo);
        int br = wn * 64 + i * 16 + ln;
        bf[i] = *(const bf16x8*)(lB + br * 128 + byo);
      }
#pragma unroll
      for (int i = 0; i < 4; ++i)
#pragma unroll
        for (int j = 0; j < 4; ++j)
          acc[i][j] = __builtin_amdgcn_mfma_f32_16x16x32_bf16(af[i], bf[j], acc[i][j], 0, 0, 0);
    }
  }

#pragma unroll
  for (int j = 0; j < 4; ++j) {
    int col = n0 + wn * 64 + j * 16 + ln;
    float bv = bias[col];
    if (MODE == 0) {
#pragma unroll
      for (int i = 0; i < 4; ++i) {
        int row0 = m0 + wm * 64 + i * 16 + g * 4;
#pragma unroll
        for (int r = 0; r < 4; ++r)
          ((float*)C0)[(size_t)(row0 + r) * N + col] = acc[i][j][r] + bv;
      }
    } else if (col < 1024) {
      float scale = (col < 512) ? (0.125f * LOG2E) : 1.0f;
#pragma unroll
      for (int i = 0; i < 4; ++i) {
        int row0 = m0 + wm * 64 + i * 16 + g * 4;
#pragma unroll
        for (int r = 0; r < 4; ++r)
          ((__bf16*)C0)[(size_t)(row0 + r) * 1024 + col] = (__bf16)((acc[i][j][r] + bv) * scale);
      }
    } else {
      int h = (col - 1024) >> 6;
      int d = (col - 1024) & 63;
#pragma unroll
      for (int i = 0; i < 4; ++i) {
        int row0 = m0 + wm * 64 + i * 16 + g * 4;
        int b = row0 >> 10;
        bf16x4 pk;
#pragma unroll
        for (int r = 0; r < 4; ++r) pk[r] = (__bf16)(acc[i][j][r] + bv);
        *(bf16x4*)(vT + (((size_t)b * 8 + h) * 64 + d) * 1024 + (row0 & 1023)) = pk;
      }
    }
  }
}

// ---------------- fused flash attention: QT=32/wave, 2-way k-split --------
// 512 blocks (XCD-swizzled), 512 threads = 8 waves. Wave = (head hg*4+wid&3,
// k-half wid>>2): 32 q rows x 512 k each, 16 iterations. No-max log2 softmax
// -> k-split partials (o,l) combine by simple summation at the end (one LDS
// exchange + one barrier). All frag/staging layouts are R8-validated.
template <int TABLE>
__global__ __launch_bounds__(512, 4) void attn_fused(
    const __bf16* __restrict__ qk,    // [B][N][1024]: q(log2-prescaled)|k
    const __bf16* __restrict__ vT,    // [B*8][64 d][1024 k]
    const _Float16* __restrict__ ebT, // f16 bias table (TABLE=1)
    const float* __restrict__ gbias,  // [B][N][N]    (TABLE=0)
    const float* __restrict__ bstr,   // [1]
    __bf16* __restrict__ attn) {      // [B][N][512]
  __shared__ __align__(16) char smem[81920];
  const int t = threadIdx.x;
  const int lane = t & 63;
  const int wid = t >> 6;                 // 0..7
  const int g = lane >> 4, ln = lane & 15;
  const int wg = ((blockIdx.x & 7) << 6) + (blockIdx.x >> 3);
  const int b = wg >> 6;
  const int rem = wg & 63;
  const int qt2 = rem >> 1;               // 32-row q tile, 0..31
  const int hg = rem & 1;
  const int h = hg * 4 + (wid & 3);
  const int kp = wid >> 2;                // k-split half, 0/1
  const int q0 = qt2 << 5;

  char* Ks = smem + wid * 10240;  // [32 k][128B] swizzled (wave-private)
  char* Vs = Ks + 4096;           // [64 d][64B] swizzled
  char* Ps = Ks + 8192;           // [2 mi][16 q][64B] P round-trip

  const float alpha = 1.f / (1.f + __expf(-bstr[0]));
  const float bsc = 10.f * alpha * LOG2E;

  // Q A-frags: row = q0 + mi*16 + ln, k-dim = ks*32 + g*8 + j
  bf16x8 qf[2][2];
#pragma unroll
  for (int mi = 0; mi < 2; ++mi)
#pragma unroll
    for (int ks = 0; ks < 2; ++ks)
      qf[mi][ks] = *(const bf16x8*)(qk + ((size_t)b * 1024 + q0 + mi * 16 + ln) * 1024 +
                                    h * 64 + ks * 32 + g * 8);

  float l_acc[2][4] = {};
  f32x4 o_acc[2][4] = {};

  const int krow = lane >> 3;
  const int ksrc = ((lane & 7) * 16) ^ (krow << 4);
  const int vrow = lane >> 2;
  const int vsrc = ((lane & 3) * 16) ^ ((vrow & 3) << 4);

  const char* qkb = (const char*)qk + (size_t)b * 1024 * 2048;
  const char* vTb = (const char*)vT + (size_t)(b * 8 + h) * 64 * 2048;
  const float* gbb = gbias + (size_t)b * 1024 * 1024 + q0;
  // ebT element offset: ((b*64+qt)*32+kt)*512 + lane*8; qt = 2*qt2 + mi
  const _Float16* ebp = ebT + (size_t)((b * 64 + 2 * qt2) * 32) * 512 + lane * 8;

  const int kt0 = kp * 16;  // this wave's k-tile range [kt0, kt0+16)

  // bias state
  f16x8 ebc[2], ebn[2];
  float bp_a[16], bp_b[16];
  if (TABLE) {
#pragma unroll
    for (int mi = 0; mi < 2; ++mi)
      ebc[mi] = *(const f16x8*)(ebp + (size_t)(mi * 32 + kt0) * 512);
  } else {
#pragma unroll
    for (int mi = 0; mi < 2; ++mi)
#pragma unroll
      for (int ni = 0; ni < 2; ++ni)
#pragma unroll
        for (int r = 0; r < 4; ++r) {
          bp_a[mi * 8 + ni * 4 + r] =
              gbb[(size_t)(kt0 * 32 + ni * 16 + ln) * 1024 + mi * 16 + g * 4 + r];
          bp_b[mi * 8 + ni * 4 + r] =
              gbb[(size_t)(kt0 * 32 + 32 + ni * 16 + ln) * 1024 + mi * 16 + g * 4 + r];
        }
  }

  // stage tile kt0
#pragma unroll
  for (int c = 0; c < 4; ++c) {
    async_load16(qkb + (size_t)(kt0 * 32 + c * 8 + krow) * 2048 + 1024 + h * 128 + ksrc,
                 Ks + c * 1024 + lane * 16);
    async_load16(vTb + (size_t)(c * 16 + vrow) * 2048 + (size_t)(kt0 * 32) * 2 + vsrc,
                 Vs + c * 1024 + lane * 16);
  }

  for (int kt = 0; kt < 16; ++kt) {
    const int ktA = kt0 + kt;
    const int ktN = (kt < 15) ? ktA + 1 : kt0;  // next tile (wrap in own half)
    const int k1 = ktN * 32;

    // drain staged K/V(t) + bias loads (issued >= ~full iteration ago)
    asm volatile("s_waitcnt vmcnt(0)" ::: "memory");
    __builtin_amdgcn_sched_barrier(0);

    // bias(t) -> C-operands; issue next bias load(s)
    f32x4 lbf[2][2];
    if (TABLE) {
#pragma unroll
      for (int mi = 0; mi < 2; ++mi)
#pragma unroll
        for (int ni = 0; ni < 2; ++ni)
#pragma unroll
          for (int r = 0; r < 4; ++r)
            lbf[mi][ni][r] = (float)ebc[mi][ni * 4 + r];
#pragma unroll
      for (int mi = 0; mi < 2; ++mi)
        ebn[mi] = *(const f16x8*)(ebp + (size_t)(mi * 32 + ktN) * 512);
    } else {
      const int ktP = kt0 + ((kt + 2 < 16) ? kt + 2 : 0);
#pragma unroll
      for (int mi = 0; mi < 2; ++mi)
#pragma unroll
        for (int ni = 0; ni < 2; ++ni)
#pragma unroll
          for (int r = 0; r < 4; ++r)
            lbf[mi][ni][r] = bsc * (1.f / (1.f + __expf(-bp_a[mi * 8 + ni * 4 + r])) - 0.5f);
#pragma unroll
      for (int i = 0; i < 16; ++i) bp_a[i] = bp_b[i];
#pragma unroll
      for (int mi = 0; mi < 2; ++mi)
#pragma unroll
        for (int ni = 0; ni < 2; ++ni)
#pragma unroll
          for (int r = 0; r < 4; ++r)
            bp_b[mi * 8 + ni * 4 + r] =
                gbb[(size_t)(ktP * 32 + ni * 16 + ln) * 1024 + mi * 16 + g * 4 + r];
    }

    // K + V frag reads (tile t), single lgkm wait
    bf16x8 kf[2][2], vf[4];
#pragma unroll
    for (int ni = 0; ni < 2; ++ni) {
      int br = ni * 16 + ln;
      int sw = (br & 7) << 4;
#pragma unroll
      for (int ks = 0; ks < 2; ++ks)
        kf[ni][ks] = *(const bf16x8*)(Ks + br * 128 + ((ks * 64 + g * 16) ^ sw));
    }
#pragma unroll
    for (int di = 0; di < 4; ++di)
      vf[di] = *(const bf16x8*)(Vs + (di * 16 + ln) * 64 + ((g * 16) ^ ((ln & 3) << 4)));
    asm volatile("s_waitcnt lgkmcnt(0)" ::: "memory");
    __builtin_amdgcn_sched_barrier(0);

    // stage K(t+1), V(t+1): frag data already in VGPRs; ~full iter coverage
#pragma unroll
    for (int c = 0; c < 4; ++c) {
      async_load16(qkb + (size_t)(k1 + c * 8 + krow) * 2048 + 1024 + h * 128 + ksrc,
                   Ks + c * 1024 + lane * 16);
      async_load16(vTb + (size_t)(c * 16 + vrow) * 2048 + (size_t)k1 * 2 + vsrc,
                   Vs + c * 1024 + lane * 16);
    }
    __builtin_amdgcn_sched_barrier(0);

    // S = QK^T + bias via C-operand (D: q = mi*16 + 4g + r, key = ni*16 + ln)
    f32x4 s[2][2];
#pragma unroll
    for (int mi = 0; mi < 2; ++mi)
#pragma unroll
      for (int ni = 0; ni < 2; ++ni) {
        s[mi][ni] = __builtin_amdgcn_mfma_f32_16x16x32_bf16(
            qf[mi][0], kf[ni][0], lbf[mi][ni], 0, 0, 0);
        s[mi][ni] = __builtin_amdgcn_mfma_f32_16x16x32_bf16(
            qf[mi][1], kf[ni][1], s[mi][ni], 0, 0, 0);
      }

    // p = 2^s; accumulate l; P round-trip through LDS
#pragma unroll
    for (int mi = 0; mi < 2; ++mi)
#pragma unroll
      for (int r = 0; r < 4; ++r) {
        float p0 = fast_exp2(s[mi][0][r]);
        float p1 = fast_exp2(s[mi][1][r]);
        s[mi][0][r] = p0; s[mi][1][r] = p1;
        l_acc[mi][r] += p0 + p1;
      }
#pragma unroll
    for (int mi = 0; mi < 2; ++mi)
#pragma unroll
      for (int ni = 0; ni < 2; ++ni)
#pragma unroll
        for (int r = 0; r < 4; ++r) {
          int q = g * 4 + r;
          *(__bf16*)(Ps + mi * 1024 + q * 64 +
                     ((ni * 32 + ln * 2) ^ (((q >> 1) & 3) << 4))) = (__bf16)s[mi][ni][r];
        }
    bf16x8 pf[2];
#pragma unroll
    for (int mi = 0; mi < 2; ++mi)
      pf[mi] = *(const bf16x8*)(Ps + mi * 1024 + ln * 64 +
                                ((g * 16) ^ (((ln >> 1) & 3) << 4)));

    // O += P V
#pragma unroll
    for (int mi = 0; mi < 2; ++mi)
#pragma unroll
      for (int di = 0; di < 4; ++di)
        o_acc[mi][di] = __builtin_amdgcn_mfma_f32_16x16x32_bf16(pf[mi], vf[di], o_acc[mi][di], 0, 0, 0);

    if (TABLE) { ebc[0] = ebn[0]; ebc[1] = ebn[1]; }
  }

  // ---- k-split combine: partials sum (no-max softmax => plain addition) ----
  if (kp == 1) {
#pragma unroll
    for (int mi = 0; mi < 2; ++mi) {
#pragma unroll
      for (int di = 0; di < 4; ++di)
        *(f32x4*)(Ks + (mi * 4 + di) * 1024 + lane * 16) = o_acc[mi][di];
      f32x4 lv = {l_acc[mi][0], l_acc[mi][1], l_acc[mi][2], l_acc[mi][3]};
      *(f32x4*)(Ps + mi * 1024 + lane * 16) = lv;
    }
  }
  __syncthreads();
  if (kp == 0) {
    const char* src = smem + (wid + 4) * 10240;
#pragma unroll
    for (int mi = 0; mi < 2; ++mi) {
#pragma unroll
      for (int di = 0; di < 4; ++di) {
        f32x4 ov = *(const f32x4*)(src + (mi * 4 + di) * 1024 + lane * 16);
#pragma unroll
        for (int r = 0; r < 4; ++r) o_acc[mi][di][r] += ov[r];
      }
      f32x4 lv = *(const f32x4*)(src + 8192 + mi * 1024 + lane * 16);
#pragma unroll
      for (int r = 0; r < 4; ++r) l_acc[mi][r] += lv[r];
    }
    // reduce l over the 16 ln-lanes, normalize, store
#pragma unroll
    for (int mi = 0; mi < 2; ++mi)
#pragma unroll
      for (int r = 0; r < 4; ++r) {
        float rs = l_acc[mi][r];
#pragma unroll
        for (int off = 1; off < 16; off <<= 1)
          rs += __shfl_xor(rs, off, 64);
        float inv = 1.f / rs;
        int q = q0 + mi * 16 + g * 4 + r;
#pragma unroll
        for (int di = 0; di < 4; ++di)
          attn[((size_t)b * 1024 + q) * 512 + h * 64 + di * 16 + ln] =
              (__bf16)(o_acc[mi][di][r] * inv);
      }
  }
}

extern "C" void kernel_launch(void* const* d_in, const int* in_sizes, int n_in,
                              void* d_out, int out_size, void* d_ws, size_t ws_size,
                              hipStream_t stream) {
  const float* x     = (const float*)d_in[0];
  const float* gb    = (const float*)d_in[1];
  const float* w_in  = (const float*)d_in[2];
  const float* b_in  = (const float*)d_in[3];
  const float* w_out = (const float*)d_in[4];
  const float* b_out = (const float*)d_in[5];
  const float* bstr  = (const float*)d_in[6];

  char* ws = (char*)d_ws;
  __bf16* qk    = (__bf16*)(ws);                      // 16,777,216 B
  __bf16* vT    = (__bf16*)(ws + 16777216);           //  8,388,608 B
  __bf16* xb    = (__bf16*)(ws + 25165824);           //  8,388,608 B
  __bf16* w1    = (__bf16*)(ws + 33554432);           //  1,572,864 B
  __bf16* w2    = (__bf16*)(ws + 35127296);           //    524,288 B
  _Float16* ebT = (_Float16*)(ws + 35651584);         // 16,777,216 B (if fits)
  __bf16* attn_buf = xb;  // alias: x_bf16 dead after GEMM1

  const bool use_tab = ws_size >= (size_t)35651584 + 16777216;

  cvt_f32_bf16<<<2048, 256, 0, stream>>>(x, xb, (8 * 1024 * 512) / 4);
  cvt_f32_bf16<<<768, 256, 0, stream>>>(w_in, w1, (1536 * 512) / 4);
  cvt_f32_bf16<<<256, 256, 0, stream>>>(w_out, w2, (512 * 512) / 4);

  gemm_bt<1><<<dim3(12, 64), 256, 0, stream>>>(xb, w1, b_in, qk, vT, 8192, 1536, 512);
  if (use_tab) {
    build_ebias<<<4096, 256, 0, stream>>>(gb, bstr, ebT);
    attn_fused<1><<<512, 512, 0, stream>>>(qk, vT, ebT, gb, bstr, attn_buf);
  } else {
    attn_fused<0><<<512, 512, 0, stream>>>(qk, vT, ebT, gb, bstr, attn_buf);
  }
  gemm_bt<0><<<dim3(4, 64), 256, 0, stream>>>(attn_buf, w2, b_out, d_out, nullptr, 8192, 512, 512);
}

// Round 10
// 123.463 us; speedup vs baseline: 1.1185x; 1.1185x over previous
//
#include <hip/hip_runtime.h>

typedef __attribute__((ext_vector_type(8))) __bf16 bf16x8;
typedef __attribute__((ext_vector_type(4))) __bf16 bf16x4;
typedef __attribute__((ext_vector_type(4))) float f32x4;
typedef __attribute__((ext_vector_type(8))) _Float16 f16x8;

#define LOG2E 1.44269504088896340736f

__device__ __forceinline__ void async_load16(const void* g, void* l) {
  __builtin_amdgcn_global_load_lds(
      (const __attribute__((address_space(1))) void*)g,
      (__attribute__((address_space(3))) void*)l, 16, 0, 0);
}

__device__ __forceinline__ float fast_exp2(float x) {
#if __has_builtin(__builtin_amdgcn_exp2f)
  return __builtin_amdgcn_exp2f(x);
#else
  return __expf(x * 0.6931471805599453f);
#endif
}

// ---------------- fp32 -> bf16 convert, 3 segments in one launch ----------
__global__ void cvt3(const float* __restrict__ a, __bf16* __restrict__ oa, int na4,
                     const float* __restrict__ b, __bf16* __restrict__ ob, int nb4,
                     const float* __restrict__ c, __bf16* __restrict__ oc, int nc4) {
  int i = blockIdx.x * blockDim.x + threadIdx.x;
  int n = na4 + nb4 + nc4;
  int stride = gridDim.x * blockDim.x;
  for (; i < n; i += stride) {
    const float4* s;
    bf16x4* d;
    int j;
    if (i < na4) { s = (const float4*)a; d = (bf16x4*)oa; j = i; }
    else if (i < na4 + nb4) { s = (const float4*)b; d = (bf16x4*)ob; j = i - na4; }
    else { s = (const float4*)c; d = (bf16x4*)oc; j = i - na4 - nb4; }
    float4 v = s[j];
    bf16x4 o;
    o[0] = (__bf16)v.x; o[1] = (__bf16)v.y; o[2] = (__bf16)v.z; o[3] = (__bf16)v.w;
    d[j] = o;
  }
}

// ---------------- log2-domain bias table, per-lane fragment layout ----------
// ebT f16x8 index (((b*64+qt)*32+kt)*64 + lane); element [ni*4+r] =
//   (sigmoid(gbias[b][kt*32+16ni+ln][qt*16+4g+r]) - 0.5) * 10*alpha*log2e
// float4 source reads: full 64B-line utilization.
__global__ __launch_bounds__(256) void build_ebias(
    const float* __restrict__ gbias, const float* __restrict__ bstr,
    _Float16* __restrict__ ebT) {
  const int gid = blockIdx.x * 256 + threadIdx.x;  // 4096 blocks
  const int lane = gid & 63;
  const int kt = (gid >> 6) & 31;
  const int qt = (gid >> 11) & 63;
  const int b = gid >> 17;
  const int g = lane >> 4, ln = lane & 15;
  const float alpha = 1.f / (1.f + __expf(-bstr[0]));
  const float bsc = 10.f * alpha * LOG2E;
  const float* base = gbias + (size_t)(b * 1024 + kt * 32 + ln) * 1024 + qt * 16 + g * 4;
  float4 va = *(const float4*)(base);                  // ni=0 row
  float4 vb = *(const float4*)(base + 16 * 1024);      // ni=1 row
  float sv[8] = {va.x, va.y, va.z, va.w, vb.x, vb.y, vb.z, vb.w};
  f16x8 o;
#pragma unroll
  for (int i = 0; i < 8; ++i)
    o[i] = (_Float16)((1.f / (1.f + __expf(-sv[i])) - 0.5f) * bsc);
  *(f16x8*)(ebT + (size_t)gid * 8) = o;
}

// ---------------- C = (A @ Bm^T + bias) [*scale] ----------------
template <int MODE>
__global__ __launch_bounds__(256) void gemm_bt(
    const __bf16* __restrict__ A, const __bf16* __restrict__ Bm,
    const float* __restrict__ bias, void* __restrict__ C0,
    __bf16* __restrict__ vT, int M, int N, int K) {
  __shared__ __align__(16) char smem[32768];
  char* lA = smem;
  char* lB = smem + 16384;
  const int t = threadIdx.x;
  const int lane = t & 63;
  const int wid = t >> 6;
  const int wm = wid >> 1, wn = wid & 1;
  const int g = lane >> 4, ln = lane & 15;
  const int m0 = blockIdx.y * 128;
  const int n0 = blockIdx.x * 128;

  const int srow = t >> 3;
  const int sswz = ((t & 7) * 16) ^ ((srow & 7) << 4);
  const size_t KB = (size_t)K * 2;
  const char* gA = (const char*)A + (size_t)m0 * KB;
  const char* gB = (const char*)Bm + (size_t)n0 * KB;

  f32x4 acc[4][4] = {};

  for (int k0 = 0; k0 < K; k0 += 64) {
    __syncthreads();
#pragma unroll
    for (int c = 0; c < 4; ++c) {
      int row = srow + 32 * c;
      async_load16(gA + (size_t)row * KB + k0 * 2 + sswz, lA + c * 4096 + t * 16);
      async_load16(gB + (size_t)row * KB + k0 * 2 + sswz, lB + c * 4096 + t * 16);
    }
    __syncthreads();
#pragma unroll
    for (int ks = 0; ks < 2; ++ks) {
      bf16x8 af[4], bf[4];
#pragma unroll
      for (int i = 0; i < 4; ++i) {
        int ar = wm * 64 + i * 16 + ln;
        int byo = (ks * 64 + g * 16) ^ ((ar & 7) << 4);
        af[i] = *(const bf16x8*)(lA + ar * 128 + byo);
        int br = wn * 64 + i * 16 + ln;
        bf[i] = *(const bf16x8*)(lB + br * 128 + byo);
      }
#pragma unroll
      for (int i = 0; i < 4; ++i)
#pragma unroll
        for (int j = 0; j < 4; ++j)
          acc[i][j] = __builtin_amdgcn_mfma_f32_16x16x32_bf16(af[i], bf[j], acc[i][j], 0, 0, 0);
    }
  }

#pragma unroll
  for (int j = 0; j < 4; ++j) {
    int col = n0 + wn * 64 + j * 16 + ln;
    float bv = bias[col];
    if (MODE == 0) {
#pragma unroll
      for (int i = 0; i < 4; ++i) {
        int row0 = m0 + wm * 64 + i * 16 + g * 4;
#pragma unroll
        for (int r = 0; r < 4; ++r)
          ((float*)C0)[(size_t)(row0 + r) * N + col] = acc[i][j][r] + bv;
      }
    } else if (col < 1024) {
      float scale = (col < 512) ? (0.125f * LOG2E) : 1.0f;
#pragma unroll
      for (int i = 0; i < 4; ++i) {
        int row0 = m0 + wm * 64 + i * 16 + g * 4;
#pragma unroll
        for (int r = 0; r < 4; ++r)
          ((__bf16*)C0)[(size_t)(row0 + r) * 1024 + col] = (__bf16)((acc[i][j][r] + bv) * scale);
      }
    } else {
      int h = (col - 1024) >> 6;
      int d = (col - 1024) & 63;
#pragma unroll
      for (int i = 0; i < 4; ++i) {
        int row0 = m0 + wm * 64 + i * 16 + g * 4;
        int b = row0 >> 10;
        bf16x4 pk;
#pragma unroll
        for (int r = 0; r < 4; ++r) pk[r] = (__bf16)(acc[i][j][r] + bv);
        *(bf16x4*)(vT + (((size_t)b * 8 + h) * 64 + d) * 1024 + (row0 & 1023)) = pk;
      }
    }
  }
}

// ---------------- fused flash attention: counted double-buffer pipeline ----
// 1024 blocks (4 waves each; bijective XCD swizzle, one batch per XCD), wave
// = one head x 16 q rows x 32 k-tiles. No-max log2 softmax (R8-validated).
// ALL in-loop VMEM = global_load_lds, exactly 9 ops per iteration in one
// fenced block [eb, K x4, V x4] -> steady-state wait vmcnt(9): tile t's loads
// retire ~2 iterations after issue; waits are ~free. K/V/eb double-buffered
// (parity via 2x-unrolled body); P round-trip single-buffered.
__global__ __launch_bounds__(256, 2) void attn_fused(
    const __bf16* __restrict__ qk,    // [B][N][1024]: q(log2-prescaled)|k
    const __bf16* __restrict__ vT,    // [B*8][64 d][1024 k]
    const _Float16* __restrict__ ebT, // f16 bias table
    __bf16* __restrict__ attn) {      // [B][N][512]
  __shared__ __align__(16) char smem[77824];
  const int t = threadIdx.x;
  const int lane = t & 63;
  const int wid = t >> 6;               // 0..3
  const int g = lane >> 4, ln = lane & 15;
  const int wg = ((blockIdx.x & 7) << 7) + (blockIdx.x >> 3);  // bijective, 1024%8==0
  const int b = wg >> 7;
  const int rem = wg & 127;
  const int qt = rem >> 1;              // 0..63
  const int h = (rem & 1) * 4 + wid;    // head
  const int q0 = qt << 4;

  char* base = smem + wid * 19456;
  char* K0 = base;            // [32 k][128B] swizzled
  char* K1 = base + 4096;
  char* V0 = base + 8192;     // [64 d][64B] swizzled
  char* V1 = base + 12288;
  char* E0 = base + 16384;    // [64 lane][16B] eb tile
  char* E1 = base + 17408;
  char* Ps = base + 18432;    // [16 q][64B] P round-trip

  // Q A-frags: row = ln, k-dim = ks*32 + g*8 + j (prescaled by log2e/8)
  bf16x8 qf[2];
#pragma unroll
  for (int ks = 0; ks < 2; ++ks)
    qf[ks] = *(const bf16x8*)(qk + ((size_t)b * 1024 + q0 + ln) * 1024 +
                              h * 64 + ks * 32 + g * 8);

  float l_acc[4] = {0.f, 0.f, 0.f, 0.f};
  f32x4 o_acc[4] = {};

  const int krow = lane >> 3;
  const int ksrc = ((lane & 7) * 16) ^ (krow << 4);
  const int vrow = lane >> 2;
  const int vsrc = ((lane & 3) * 16) ^ ((vrow & 3) << 4);

  const char* qkb = (const char*)qk + (size_t)b * 1024 * 2048;
  const char* vTb = (const char*)vT + (size_t)(b * 8 + h) * 64 * 2048;
  const char* ebg = (const char*)ebT + (size_t)((b * 64 + qt) * 32) * 1024 + lane * 16;

  // stage tile kt: 9 global_load_lds in fixed order [eb, K x4, V x4]
  auto stage = [&](int kt, char* Kd, char* Vd, char* Ed) {
    async_load16(ebg + (size_t)kt * 1024, Ed + lane * 16);
#pragma unroll
    for (int c = 0; c < 4; ++c)
      async_load16(qkb + (size_t)(kt * 32 + c * 8 + krow) * 2048 + 1024 + h * 128 + ksrc,
                   Kd + c * 1024 + lane * 16);
#pragma unroll
    for (int c = 0; c < 4; ++c)
      async_load16(vTb + (size_t)(c * 16 + vrow) * 2048 + (size_t)(kt * 32) * 2 + vsrc,
                   Vd + c * 1024 + lane * 16);
  };

  // prologue: blocks for kt=0 (parity 0) and kt=1 (parity 1); 18 outstanding
  stage(0, K0, V0, E0);
  stage(1, K1, V1, E1);

  auto subiter = [&](int ktA, char* Kp, char* Vp, char* Ep) {
    // retire tile ktA's 9 ops (issued 2 sub-iters ago); keep ktA+1's 9 in flight
    asm volatile("s_waitcnt vmcnt(9)" ::: "memory");
    __builtin_amdgcn_sched_barrier(0);

    // LDS reads: eb tile + K frags + V frags (all from parity-p buffers)
    f16x8 ebv = *(const f16x8*)(Ep + lane * 16);
    bf16x8 kf[2][2];
#pragma unroll
    for (int ni = 0; ni < 2; ++ni) {
      int br = ni * 16 + ln;
      int sw = (br & 7) << 4;
#pragma unroll
      for (int ks = 0; ks < 2; ++ks)
        kf[ni][ks] = *(const bf16x8*)(Kp + br * 128 + ((ks * 64 + g * 16) ^ sw));
    }
    bf16x8 vf[4];
#pragma unroll
    for (int di = 0; di < 4; ++di)
      vf[di] = *(const bf16x8*)(Vp + (di * 16 + ln) * 64 + ((g * 16) ^ ((ln & 3) << 4)));
    asm volatile("s_waitcnt lgkmcnt(0)" ::: "memory");
    __builtin_amdgcn_sched_barrier(0);

    // fenced 9-op vmem block: stage tile ktA+2 into the just-freed buffers
    stage((ktA + 2) & 31, Kp, Vp, Ep);
    __builtin_amdgcn_sched_barrier(0);

    // S = QK^T + bias via C-operand (D: q = 4g + r, key = ni*16 + ln)
    f32x4 lbf0 = {(float)ebv[0], (float)ebv[1], (float)ebv[2], (float)ebv[3]};
    f32x4 lbf1 = {(float)ebv[4], (float)ebv[5], (float)ebv[6], (float)ebv[7]};
    f32x4 s[2];
    s[0] = __builtin_amdgcn_mfma_f32_16x16x32_bf16(qf[0], kf[0][0], lbf0, 0, 0, 0);
    s[0] = __builtin_amdgcn_mfma_f32_16x16x32_bf16(qf[1], kf[0][1], s[0], 0, 0, 0);
    s[1] = __builtin_amdgcn_mfma_f32_16x16x32_bf16(qf[0], kf[1][0], lbf1, 0, 0, 0);
    s[1] = __builtin_amdgcn_mfma_f32_16x16x32_bf16(qf[1], kf[1][1], s[1], 0, 0, 0);

    // p = 2^s; accumulate l; P round-trip through LDS (wave-order safe)
#pragma unroll
    for (int r = 0; r < 4; ++r) {
      float p0 = fast_exp2(s[0][r]);
      float p1 = fast_exp2(s[1][r]);
      s[0][r] = p0; s[1][r] = p1;
      l_acc[r] += p0 + p1;
    }
#pragma unroll
    for (int ni = 0; ni < 2; ++ni)
#pragma unroll
      for (int r = 0; r < 4; ++r) {
        int q = g * 4 + r;
        *(__bf16*)(Ps + q * 64 + ((ni * 32 + ln * 2) ^ (((q >> 1) & 3) << 4))) =
            (__bf16)s[ni][r];
      }
    bf16x8 pf = *(const bf16x8*)(Ps + ln * 64 + ((g * 16) ^ (((ln >> 1) & 3) << 4)));

    // O += P V
#pragma unroll
    for (int di = 0; di < 4; ++di)
      o_acc[di] = __builtin_amdgcn_mfma_f32_16x16x32_bf16(pf, vf[di], o_acc[di], 0, 0, 0);
  };

  for (int kt2 = 0; kt2 < 16; ++kt2) {
    subiter(2 * kt2, K0, V0, E0);
    subiter(2 * kt2 + 1, K1, V1, E1);
  }

  // reduce l over the 16 ln-lanes, normalize, store
#pragma unroll
  for (int r = 0; r < 4; ++r) {
    float rs = l_acc[r];
#pragma unroll
    for (int off = 1; off < 16; off <<= 1)
      rs += __shfl_xor(rs, off, 64);
    float inv = 1.f / rs;
    int q = q0 + g * 4 + r;
#pragma unroll
    for (int di = 0; di < 4; ++di)
      attn[((size_t)b * 1024 + q) * 512 + h * 64 + di * 16 + ln] =
          (__bf16)(o_acc[di][r] * inv);
  }
}

extern "C" void kernel_launch(void* const* d_in, const int* in_sizes, int n_in,
                              void* d_out, int out_size, void* d_ws, size_t ws_size,
                              hipStream_t stream) {
  const float* x     = (const float*)d_in[0];
  const float* gb    = (const float*)d_in[1];
  const float* w_in  = (const float*)d_in[2];
  const float* b_in  = (const float*)d_in[3];
  const float* w_out = (const float*)d_in[4];
  const float* b_out = (const float*)d_in[5];
  const float* bstr  = (const float*)d_in[6];

  char* ws = (char*)d_ws;
  __bf16* qk    = (__bf16*)(ws);                      // 16,777,216 B
  __bf16* vT    = (__bf16*)(ws + 16777216);           //  8,388,608 B
  __bf16* xb    = (__bf16*)(ws + 25165824);           //  8,388,608 B
  __bf16* w1    = (__bf16*)(ws + 33554432);           //  1,572,864 B
  __bf16* w2    = (__bf16*)(ws + 35127296);           //    524,288 B
  _Float16* ebT = (_Float16*)(ws + 35651584);         // 16,777,216 B (52.4MB tot;
                                                      // R8/R9 confirmed ws fits)
  __bf16* attn_buf = xb;  // alias: x_bf16 dead after GEMM1

  cvt3<<<2560, 256, 0, stream>>>(x, xb, (8 * 1024 * 512) / 4,
                                 w_in, w1, (1536 * 512) / 4,
                                 w_out, w2, (512 * 512) / 4);
  build_ebias<<<4096, 256, 0, stream>>>(gb, bstr, ebT);

  gemm_bt<1><<<dim3(12, 64), 256, 0, stream>>>(xb, w1, b_in, qk, vT, 8192, 1536, 512);
  attn_fused<<<1024, 256, 0, stream>>>(qk, vT, ebT, attn_buf);
  gemm_bt<0><<<dim3(4, 64), 256, 0, stream>>>(attn_buf, w2, b_out, d_out, nullptr, 8192, 512, 512);
}

// Round 11
// 123.307 us; speedup vs baseline: 1.1199x; 1.0013x over previous
//
#include <hip/hip_runtime.h>

typedef __attribute__((ext_vector_type(8))) __bf16 bf16x8;
typedef __attribute__((ext_vector_type(4))) __bf16 bf16x4;
typedef __attribute__((ext_vector_type(4))) float f32x4;
typedef __attribute__((ext_vector_type(8))) _Float16 f16x8;

#define LOG2E 1.44269504088896340736f

__device__ __forceinline__ void async_load16(const void* g, void* l) {
  __builtin_amdgcn_global_load_lds(
      (const __attribute__((address_space(1))) void*)g,
      (__attribute__((address_space(3))) void*)l, 16, 0, 0);
}

__device__ __forceinline__ float fast_exp2(float x) {
#if __has_builtin(__builtin_amdgcn_exp2f)
  return __builtin_amdgcn_exp2f(x);
#else
  return __expf(x * 0.6931471805599453f);
#endif
}

// ---------------- fp32 -> bf16 convert, 3 segments in one launch ----------
__global__ void cvt3(const float* __restrict__ a, __bf16* __restrict__ oa, int na4,
                     const float* __restrict__ b, __bf16* __restrict__ ob, int nb4,
                     const float* __restrict__ c, __bf16* __restrict__ oc, int nc4) {
  int i = blockIdx.x * blockDim.x + threadIdx.x;
  int n = na4 + nb4 + nc4;
  int stride = gridDim.x * blockDim.x;
  for (; i < n; i += stride) {
    const float4* s;
    bf16x4* d;
    int j;
    if (i < na4) { s = (const float4*)a; d = (bf16x4*)oa; j = i; }
    else if (i < na4 + nb4) { s = (const float4*)b; d = (bf16x4*)ob; j = i - na4; }
    else { s = (const float4*)c; d = (bf16x4*)oc; j = i - na4 - nb4; }
    float4 v = s[j];
    bf16x4 o;
    o[0] = (__bf16)v.x; o[1] = (__bf16)v.y; o[2] = (__bf16)v.z; o[3] = (__bf16)v.w;
    d[j] = o;
  }
}

// ---------------- log2-domain bias table, per-lane fragment layout ----------
// ebT f16x8 index (((b*64+qt)*32+kt)*64 + lane); element [ni*4+r] =
//   (sigmoid(gbias[b][kt*32+16ni+ln][qt*16+4g+r]) - 0.5) * 10*alpha*log2e
__global__ __launch_bounds__(256) void build_ebias(
    const float* __restrict__ gbias, const float* __restrict__ bstr,
    _Float16* __restrict__ ebT) {
  const int gid = blockIdx.x * 256 + threadIdx.x;  // 4096 blocks
  const int lane = gid & 63;
  const int kt = (gid >> 6) & 31;
  const int qt = (gid >> 11) & 63;
  const int b = gid >> 17;
  const int g = lane >> 4, ln = lane & 15;
  const float alpha = 1.f / (1.f + __expf(-bstr[0]));
  const float bsc = 10.f * alpha * LOG2E;
  const float* base = gbias + (size_t)(b * 1024 + kt * 32 + ln) * 1024 + qt * 16 + g * 4;
  float4 va = *(const float4*)(base);                  // ni=0 row
  float4 vb = *(const float4*)(base + 16 * 1024);      // ni=1 row
  float sv[8] = {va.x, va.y, va.z, va.w, vb.x, vb.y, vb.z, vb.w};
  f16x8 o;
#pragma unroll
  for (int i = 0; i < 8; ++i)
    o[i] = (_Float16)((1.f / (1.f + __expf(-sv[i])) - 0.5f) * bsc);
  *(f16x8*)(ebT + (size_t)gid * 8) = o;
}

// ---------------- C = (A @ Bm^T + bias) [*scale] ----------------
template <int MODE>
__global__ __launch_bounds__(256) void gemm_bt(
    const __bf16* __restrict__ A, const __bf16* __restrict__ Bm,
    const float* __restrict__ bias, void* __restrict__ C0,
    __bf16* __restrict__ vT, int M, int N, int K) {
  __shared__ __align__(16) char smem[32768];
  char* lA = smem;
  char* lB = smem + 16384;
  const int t = threadIdx.x;
  const int lane = t & 63;
  const int wid = t >> 6;
  const int wm = wid >> 1, wn = wid & 1;
  const int g = lane >> 4, ln = lane & 15;
  const int m0 = blockIdx.y * 128;
  const int n0 = blockIdx.x * 128;

  const int srow = t >> 3;
  const int sswz = ((t & 7) * 16) ^ ((srow & 7) << 4);
  const size_t KB = (size_t)K * 2;
  const char* gA = (const char*)A + (size_t)m0 * KB;
  const char* gB = (const char*)Bm + (size_t)n0 * KB;

  f32x4 acc[4][4] = {};

  for (int k0 = 0; k0 < K; k0 += 64) {
    __syncthreads();
#pragma unroll
    for (int c = 0; c < 4; ++c) {
      int row = srow + 32 * c;
      async_load16(gA + (size_t)row * KB + k0 * 2 + sswz, lA + c * 4096 + t * 16);
      async_load16(gB + (size_t)row * KB + k0 * 2 + sswz, lB + c * 4096 + t * 16);
    }
    __syncthreads();
#pragma unroll
    for (int ks = 0; ks < 2; ++ks) {
      bf16x8 af[4], bf[4];
#pragma unroll
      for (int i = 0; i < 4; ++i) {
        int ar = wm * 64 + i * 16 + ln;
        int byo = (ks * 64 + g * 16) ^ ((ar & 7) << 4);
        af[i] = *(const bf16x8*)(lA + ar * 128 + byo);
        int br = wn * 64 + i * 16 + ln;
        bf[i] = *(const bf16x8*)(lB + br * 128 + byo);
      }
#pragma unroll
      for (int i = 0; i < 4; ++i)
#pragma unroll
        for (int j = 0; j < 4; ++j)
          acc[i][j] = __builtin_amdgcn_mfma_f32_16x16x32_bf16(af[i], bf[j], acc[i][j], 0, 0, 0);
    }
  }

#pragma unroll
  for (int j = 0; j < 4; ++j) {
    int col = n0 + wn * 64 + j * 16 + ln;
    float bv = bias[col];
    if (MODE == 0) {
#pragma unroll
      for (int i = 0; i < 4; ++i) {
        int row0 = m0 + wm * 64 + i * 16 + g * 4;
#pragma unroll
        for (int r = 0; r < 4; ++r)
          ((float*)C0)[(size_t)(row0 + r) * N + col] = acc[i][j][r] + bv;
      }
    } else if (col < 1024) {
      float scale = (col < 512) ? (0.125f * LOG2E) : 1.0f;
#pragma unroll
      for (int i = 0; i < 4; ++i) {
        int row0 = m0 + wm * 64 + i * 16 + g * 4;
#pragma unroll
        for (int r = 0; r < 4; ++r)
          ((__bf16*)C0)[(size_t)(row0 + r) * 1024 + col] = (__bf16)((acc[i][j][r] + bv) * scale);
      }
    } else {
      int h = (col - 1024) >> 6;
      int d = (col - 1024) & 63;
#pragma unroll
      for (int i = 0; i < 4; ++i) {
        int row0 = m0 + wm * 64 + i * 16 + g * 4;
        int b = row0 >> 10;
        bf16x4 pk;
#pragma unroll
        for (int r = 0; r < 4; ++r) pk[r] = (__bf16)(acc[i][j][r] + bv);
        *(bf16x4*)(vT + (((size_t)b * 8 + h) * 64 + d) * 1024 + (row0 & 1023)) = pk;
      }
    }
  }
}

// ---------------- fused flash attention: T14 reg-staged single-buffer -----
// 512 blocks (XCD-swizzled), 512 threads = 8 waves = 8 heads, QT=16, KT=32.
// Per iter: (1) issue K/V(t+1) -> REGISTERS + eb(t+1) load [pinned]; (2) LDS
// frag reads of tile t + full compute (covers the L2 latency); (3) ds_write
// staged regs into the single K/V buffers (compiler emits the counted vmcnt
// wait automatically). 9216B/wave -> 73728B/block -> 2 blocks/CU, 4 waves/SIMD.
__global__ __launch_bounds__(512, 4) void attn_fused(
    const __bf16* __restrict__ qk,    // [B][N][1024]: q(log2-prescaled)|k
    const __bf16* __restrict__ vT,    // [B*8][64 d][1024 k]
    const _Float16* __restrict__ ebT, // f16 bias table
    __bf16* __restrict__ attn) {      // [B][N][512]
  __shared__ __align__(16) char smem[73728];
  const int t = threadIdx.x;
  const int lane = t & 63;
  const int h = t >> 6;
  const int g = lane >> 4, ln = lane & 15;
  const int wg = ((blockIdx.x & 7) << 6) + (blockIdx.x >> 3);
  const int b = wg >> 6;
  const int qt = wg & 63;
  const int q0 = qt << 4;

  char* Ks = smem + h * 9216;  // [32 k][128B] swizzled (wave-private)
  char* Vs = Ks + 4096;        // [64 d][64B] swizzled
  char* Ps = Ks + 8192;        // [16 q][64B] P round-trip

  // Q A-frags: row = ln, k-dim = ks*32 + g*8 + j (prescaled by log2e/8)
  bf16x8 qf[2];
#pragma unroll
  for (int ks = 0; ks < 2; ++ks)
    qf[ks] = *(const bf16x8*)(qk + ((size_t)b * 1024 + q0 + ln) * 1024 +
                              h * 64 + ks * 32 + g * 8);

  float l_acc[4] = {0.f, 0.f, 0.f, 0.f};
  f32x4 o_acc[4] = {};

  const int krow = lane >> 3;
  const int ksrc = ((lane & 7) * 16) ^ (krow << 4);
  const int vrow = lane >> 2;
  const int vsrc = ((lane & 3) * 16) ^ ((vrow & 3) << 4);

  const char* qkb = (const char*)qk + (size_t)b * 1024 * 2048;
  const char* vTb = (const char*)vT + (size_t)(b * 8 + h) * 64 * 2048;
  const _Float16* ebp = ebT + (size_t)((b * 64 + qt) * 32) * 512 + lane * 8;

  // prologue: stage tile 0 via global_load_lds (validated primitive) + eb(0)
#pragma unroll
  for (int c = 0; c < 4; ++c) {
    async_load16(qkb + (size_t)(c * 8 + krow) * 2048 + 1024 + h * 128 + ksrc,
                 Ks + c * 1024 + lane * 16);
    async_load16(vTb + (size_t)(c * 16 + vrow) * 2048 + vsrc,
                 Vs + c * 1024 + lane * 16);
  }
  f16x8 ebc = *(const f16x8*)(ebp);
  asm volatile("s_waitcnt vmcnt(0)" ::: "memory");
  __builtin_amdgcn_sched_barrier(0);

  for (int kt = 0; kt < 32; ++kt) {
    const int ktn = (kt + 1) & 31;  // wrapped prefetch target
    const int k1 = ktn * 32;

    // [1] stage tile t+1 into REGISTERS (same per-lane src addrs as the
    //     gl_lds path -> identical LDS image after write-back) + eb(t+1)
    bf16x8 kr[4], vr[4];
#pragma unroll
    for (int c = 0; c < 4; ++c)
      kr[c] = *(const bf16x8*)(qkb + (size_t)(k1 + c * 8 + krow) * 2048 +
                               1024 + h * 128 + ksrc);
#pragma unroll
    for (int c = 0; c < 4; ++c)
      vr[c] = *(const bf16x8*)(vTb + (size_t)(c * 16 + vrow) * 2048 +
                               (size_t)k1 * 2 + vsrc);
    f16x8 ebn = *(const f16x8*)(ebp + (size_t)ktn * 512);
    __builtin_amdgcn_sched_barrier(0);  // pin load issue here

    // [2] LDS frag reads of tile t
    bf16x8 kf[2][2];
#pragma unroll
    for (int ni = 0; ni < 2; ++ni) {
      int br = ni * 16 + ln;
      int sw = (br & 7) << 4;
#pragma unroll
      for (int ks = 0; ks < 2; ++ks)
        kf[ni][ks] = *(const bf16x8*)(Ks + br * 128 + ((ks * 64 + g * 16) ^ sw));
    }
    bf16x8 vf[4];
#pragma unroll
    for (int di = 0; di < 4; ++di)
      vf[di] = *(const bf16x8*)(Vs + (di * 16 + ln) * 64 + ((g * 16) ^ ((ln & 3) << 4)));

    // S = QK^T + bias via C-operand (D: q = 4g + r, key = ni*16 + ln)
    f32x4 lbf0 = {(float)ebc[0], (float)ebc[1], (float)ebc[2], (float)ebc[3]};
    f32x4 lbf1 = {(float)ebc[4], (float)ebc[5], (float)ebc[6], (float)ebc[7]};
    f32x4 s[2];
    s[0] = __builtin_amdgcn_mfma_f32_16x16x32_bf16(qf[0], kf[0][0], lbf0, 0, 0, 0);
    s[0] = __builtin_amdgcn_mfma_f32_16x16x32_bf16(qf[1], kf[0][1], s[0], 0, 0, 0);
    s[1] = __builtin_amdgcn_mfma_f32_16x16x32_bf16(qf[0], kf[1][0], lbf1, 0, 0, 0);
    s[1] = __builtin_amdgcn_mfma_f32_16x16x32_bf16(qf[1], kf[1][1], s[1], 0, 0, 0);

    // p = 2^s; accumulate l; P round-trip through LDS
#pragma unroll
    for (int r = 0; r < 4; ++r) {
      float p0 = fast_exp2(s[0][r]);
      float p1 = fast_exp2(s[1][r]);
      s[0][r] = p0; s[1][r] = p1;
      l_acc[r] += p0 + p1;
    }
#pragma unroll
    for (int ni = 0; ni < 2; ++ni)
#pragma unroll
      for (int r = 0; r < 4; ++r) {
        int q = g * 4 + r;
        *(__bf16*)(Ps + q * 64 + ((ni * 32 + ln * 2) ^ (((q >> 1) & 3) << 4))) =
            (__bf16)s[ni][r];
      }
    bf16x8 pf = *(const bf16x8*)(Ps + ln * 64 + ((g * 16) ^ (((ln >> 1) & 3) << 4)));

    // O += P V
#pragma unroll
    for (int di = 0; di < 4; ++di)
      o_acc[di] = __builtin_amdgcn_mfma_f32_16x16x32_bf16(pf, vf[di], o_acc[di], 0, 0, 0);

    // [3] write staged regs into the (now fully-read) single buffers.
    //     DS pipe is in-order per wave; lgkmcnt(0) is cheap insurance that
    //     the tile-t reads retired. Compiler emits the vmcnt wait for kr/vr.
    __builtin_amdgcn_sched_barrier(0);
    asm volatile("s_waitcnt lgkmcnt(0)" ::: "memory");
#pragma unroll
    for (int c = 0; c < 4; ++c)
      *(bf16x8*)(Ks + c * 1024 + lane * 16) = kr[c];
#pragma unroll
    for (int c = 0; c < 4; ++c)
      *(bf16x8*)(Vs + c * 1024 + lane * 16) = vr[c];
    __builtin_amdgcn_sched_barrier(0);

    ebc = ebn;
  }

  // reduce l over the 16 ln-lanes, normalize, store
#pragma unroll
  for (int r = 0; r < 4; ++r) {
    float rs = l_acc[r];
#pragma unroll
    for (int off = 1; off < 16; off <<= 1)
      rs += __shfl_xor(rs, off, 64);
    float inv = 1.f / rs;
    int q = q0 + g * 4 + r;
#pragma unroll
    for (int di = 0; di < 4; ++di)
      attn[((size_t)b * 1024 + q) * 512 + h * 64 + di * 16 + ln] =
          (__bf16)(o_acc[di][r] * inv);
  }
}

extern "C" void kernel_launch(void* const* d_in, const int* in_sizes, int n_in,
                              void* d_out, int out_size, void* d_ws, size_t ws_size,
                              hipStream_t stream) {
  const float* x     = (const float*)d_in[0];
  const float* gb    = (const float*)d_in[1];
  const float* w_in  = (const float*)d_in[2];
  const float* b_in  = (const float*)d_in[3];
  const float* w_out = (const float*)d_in[4];
  const float* b_out = (const float*)d_in[5];
  const float* bstr  = (const float*)d_in[6];

  char* ws = (char*)d_ws;
  __bf16* qk    = (__bf16*)(ws);                      // 16,777,216 B
  __bf16* vT    = (__bf16*)(ws + 16777216);           //  8,388,608 B
  __bf16* xb    = (__bf16*)(ws + 25165824);           //  8,388,608 B
  __bf16* w1    = (__bf16*)(ws + 33554432);           //  1,572,864 B
  __bf16* w2    = (__bf16*)(ws + 35127296);           //    524,288 B
  _Float16* ebT = (_Float16*)(ws + 35651584);         // 16,777,216 B
  __bf16* attn_buf = xb;  // alias: x_bf16 dead after GEMM1

  cvt3<<<2560, 256, 0, stream>>>(x, xb, (8 * 1024 * 512) / 4,
                                 w_in, w1, (1536 * 512) / 4,
                                 w_out, w2, (512 * 512) / 4);
  build_ebias<<<4096, 256, 0, stream>>>(gb, bstr, ebT);

  gemm_bt<1><<<dim3(12, 64), 256, 0, stream>>>(xb, w1, b_in, qk, vT, 8192, 1536, 512);
  attn_fused<<<512, 512, 0, stream>>>(qk, vT, ebT, attn_buf);
  gemm_bt<0><<<dim3(4, 64), 256, 0, stream>>>(attn_buf, w2, b_out, d_out, nullptr, 8192, 512, 512);
}